// Round 10
// baseline (196.270 us; speedup 1.0000x reference)
//
#include <hip/hip_runtime.h>
#include <hip/hip_bf16.h>

#define N_ATOMS 20000
#define N_BONDS 200000
#define MAX_DEG 12
#define IN_DIM 256
#define BOND_DIM 128
#define OUT_DIM 512
#define N_HEADS 8
#define HEAD_DIM 64

typedef __attribute__((ext_vector_type(8))) short short8v;
typedef __attribute__((ext_vector_type(4))) float f32x4;

static __device__ __forceinline__ float bf2f(unsigned int u) {
    union { unsigned int i; float f; } c;
    c.i = (u & 0xffffu) << 16;
    return c.f;
}
static __device__ __forceinline__ unsigned short f2bf(float f) {
    union { float f; unsigned int i; } c;
    c.f = f;
    unsigned int x = c.i;
    x += 0x7fffu + ((x >> 16) & 1u);   // round-to-nearest-even
    return (unsigned short)(x >> 16);
}

// ---------------------------------------------------------------------------
// Wt[n][k] = bf16(W[k][n])  (N fixed 512)
// ---------------------------------------------------------------------------
__global__ void wt_kernel(const float* __restrict__ W, unsigned short* __restrict__ Wt,
                          int K) {
    int id = blockIdx.x * 256 + threadIdx.x;
    if (id >= K * 512) return;
    int n = id / K, k = id % K;
    Wt[id] = f2bf(W[(size_t)k * 512 + n]);
}

// ---------------------------------------------------------------------------
// u_edge[h][c] = sum_k W_bond[c][h*64+k] * att_edge[h][k];  c_edge[h] = b_bond.att_edge
// ---------------------------------------------------------------------------
__global__ void uedge_kernel(const float* __restrict__ Wb, const float* __restrict__ att_edge,
                             const float* __restrict__ b_bond,
                             float* __restrict__ u_edge, float* __restrict__ c_edge) {
    int tid = blockIdx.x * 256 + threadIdx.x;
    if (tid >= 1024) return;
    int h = tid >> 7, c = tid & 127;
    const float* wrow = Wb + (size_t)c * 512 + h * 64;
    const float* ae = att_edge + h * 64;
    float s = 0.f;
    #pragma unroll 8
    for (int k = 0; k < 64; ++k) s += wrow[k] * ae[k];
    u_edge[h * 128 + c] = s;
    if (c == 0) {
        float cs = 0.f;
        const float* bb = b_bond + h * 64;
        for (int k = 0; k < 64; ++k) cs += bb[k] * ae[k];
        c_edge[h] = cs;
    }
}

// ---------------------------------------------------------------------------
// Per-atom score tables from hA: s_src_all[n][h], s_dst_all[n][h].
// ---------------------------------------------------------------------------
__global__ __launch_bounds__(256) void sdots_kernel(
    const unsigned short* __restrict__ hA,
    const float* __restrict__ att_src, const float* __restrict__ att_dst,
    float* __restrict__ s_src_all, float* __restrict__ s_dst_all) {
    const int w = threadIdx.x >> 6, l = threadIdx.x & 63;
    const int n = blockIdx.x * 4 + w;
    if (n >= N_ATOMS) return;
    float4 s0 = *(const float4*)(att_src + l * 8);
    float4 s1 = *(const float4*)(att_src + l * 8 + 4);
    float4 d0 = *(const float4*)(att_dst + l * 8);
    float4 d1 = *(const float4*)(att_dst + l * 8 + 4);
    uint4 u = *(const uint4*)(hA + (size_t)n * 512 + l * 8);
    float fa[8];
    fa[0]=bf2f(u.x); fa[1]=bf2f(u.x>>16); fa[2]=bf2f(u.y); fa[3]=bf2f(u.y>>16);
    fa[4]=bf2f(u.z); fa[5]=bf2f(u.z>>16); fa[6]=bf2f(u.w); fa[7]=bf2f(u.w>>16);
    float ps = fa[0]*s0.x + fa[1]*s0.y + fa[2]*s0.z + fa[3]*s0.w
             + fa[4]*s1.x + fa[5]*s1.y + fa[6]*s1.z + fa[7]*s1.w;
    float pd = fa[0]*d0.x + fa[1]*d0.y + fa[2]*d0.z + fa[3]*d0.w
             + fa[4]*d1.x + fa[5]*d1.y + fa[6]*d1.z + fa[7]*d1.w;
    ps += __shfl_xor(ps, 1); ps += __shfl_xor(ps, 2); ps += __shfl_xor(ps, 4);
    pd += __shfl_xor(pd, 1); pd += __shfl_xor(pd, 2); pd += __shfl_xor(pd, 4);
    if ((l & 7) == 0) {
        s_src_all[n * 8 + (l >> 3)] = ps;
        s_dst_all[n * 8 + (l >> 3)] = pd;
    }
}

// ---------------------------------------------------------------------------
// ATOM GEMM (round-4, proven): tiles 64x64x64, 4 waves, XCD-chunked swizzle.
// ---------------------------------------------------------------------------
__global__ __launch_bounds__(256) void gemm_kernel(
    const float* __restrict__ A, const unsigned short* __restrict__ Wt,
    const float* __restrict__ bias, unsigned short* __restrict__ H,
    int M, int K, int nbm) {
    __shared__ unsigned short Als[64 * 64];
    __shared__ unsigned short Bls[64 * 64];
    const int t = threadIdx.x;
    const int wgid = (blockIdx.x & 7) * nbm + (blockIdx.x >> 3);
    const int bn = wgid & 7;
    const int bm = wgid >> 3;
    const int w = t >> 6;
    const int l = t & 63;

    f32x4 acc[4] = {};

    const int nk = K >> 6;
    for (int kk = 0; kk < nk; ++kk) {
        #pragma unroll
        for (int i = 0; i < 2; ++i) {
            int c = t + i * 256;
            int row = c >> 3;
            int k8 = (c & 7) << 3;
            int grow = (bm << 6) + row;
            float f[8];
            if (grow < M) {
                const float* src = A + (size_t)grow * K + (kk << 6) + k8;
                float4 v0 = *(const float4*)src;
                float4 v1 = *(const float4*)(src + 4);
                f[0] = v0.x; f[1] = v0.y; f[2] = v0.z; f[3] = v0.w;
                f[4] = v1.x; f[5] = v1.y; f[6] = v1.z; f[7] = v1.w;
            } else {
                #pragma unroll
                for (int j = 0; j < 8; ++j) f[j] = 0.f;
            }
            union { unsigned short us[8]; uint4 v; } pk;
            #pragma unroll
            for (int j = 0; j < 8; ++j) pk.us[j] = f2bf(f[j]);
            int byte = ((row << 7) + (k8 << 1)) ^ ((row & 7) << 4);
            *(uint4*)((char*)Als + byte) = pk.v;
        }
        #pragma unroll
        for (int i = 0; i < 2; ++i) {
            int c = t + i * 256;
            int row = c >> 3;
            int k8 = (c & 7) << 3;
            int gn = (bn << 6) + row;
            uint4 v = *(const uint4*)(Wt + (size_t)gn * K + (kk << 6) + k8);
            int byte = ((row << 7) + (k8 << 1)) ^ ((row & 7) << 4);
            *(uint4*)((char*)Bls + byte) = v;
        }
        __syncthreads();

        const int m = l & 15;
        const int kg = (l >> 4) << 3;
        #pragma unroll
        for (int ks = 0; ks < 2; ++ks) {
            int kcol = (ks << 5) + kg;
            int arow = (w << 4) + m;
            short8v a = *(short8v*)((char*)Als +
                (((arow << 7) + (kcol << 1)) ^ ((arow & 7) << 4)));
            #pragma unroll
            for (int nt = 0; nt < 4; ++nt) {
                int nrow = (nt << 4) + m;
                short8v b = *(short8v*)((char*)Bls +
                    (((nrow << 7) + (kcol << 1)) ^ ((nrow & 7) << 4)));
                acc[nt] = __builtin_amdgcn_mfma_f32_16x16x32_bf16(a, b, acc[nt], 0, 0, 0);
            }
        }
        __syncthreads();
    }

    const int m = l & 15;
    const int rbase = (bm << 6) + (w << 4) + ((l >> 4) << 2);
    #pragma unroll
    for (int nt = 0; nt < 4; ++nt) {
        int col = (bn << 6) + (nt << 4) + m;
        float bv = bias[col];
        #pragma unroll
        for (int r = 0; r < 4; ++r) {
            int grow = rbase + r;
            if (grow < M) H[(size_t)grow * 512 + col] = f2bf(acc[nt][r] + bv);
        }
    }
}

// ---------------------------------------------------------------------------
// Fused attention v3: per-lane softmax for OWN head (h = l>>3); edge-score
// computed INLINE from the edge row already held in registers:
//   se = edge[ib] . u_edge[h] + c_edge[h]
// via 16 in-reg FMAs + 3-step shfl_xor reduce within the 8-lane head group
// (xor 1,2,4 stays inside the group). Kills the escore kernel and its
// duplicate 102 MB edge read. Lane l: atom-value channels l*8..+8, z-part
// edge channels (l&7)*16..+16. Z[n][h][128] bf16 out.
// ---------------------------------------------------------------------------
__global__ __launch_bounds__(256) void attn_kernel(
    const unsigned short* __restrict__ hA,
    const float* __restrict__ edge,
    const float* __restrict__ s_src_all,
    const float* __restrict__ s_dst_all,
    const float* __restrict__ u_edge,
    const float* __restrict__ c_edge,
    const int* __restrict__ a2a,
    const int* __restrict__ a2b,
    float* __restrict__ out,
    unsigned short* __restrict__ Z) {
    const int w = threadIdx.x >> 6;
    const int l = threadIdx.x & 63;
    const int n = blockIdx.x * 4 + w;
    if (n >= N_ATOMS) return;
    const int h = l >> 3, sub = l & 7;

    const float ss = s_src_all[n * 8 + h];
    // u_edge slice for this lane's 16 edge channels + c_edge[h]
    const float* up = u_edge + h * 128 + sub * 16;
    const float4 ue0 = *(const float4*)(up);
    const float4 ue1 = *(const float4*)(up + 4);
    const float4 ue2 = *(const float4*)(up + 8);
    const float4 ue3 = *(const float4*)(up + 12);
    const float ce = c_edge[h];

    float mrun = -1e30f, lsum = 0.f;
    float acc[8];
    float z[16];
    #pragma unroll
    for (int j = 0; j < 8; ++j) acc[j] = 0.f;
    #pragma unroll
    for (int j = 0; j < 16; ++j) z[j] = 0.f;

    const int* pa = a2a + n * MAX_DEG;
    const int* pb = a2b + n * MAX_DEG;

    #pragma unroll
    for (int d = 0; d < MAX_DEG; ++d) {
        const int ia = pa[d];
        const int ib = pb[d];
        const bool valid = (ia != 0);

        const float sd = s_dst_all[ia * 8 + h];
        uint4 ua = *(const uint4*)(hA + (size_t)ia * 512 + l * 8);
        const float* ep = edge + (size_t)ib * 128 + sub * 16;
        float4 e0 = *(const float4*)(ep);
        float4 e1 = *(const float4*)(ep + 4);
        float4 e2 = *(const float4*)(ep + 8);
        float4 e3 = *(const float4*)(ep + 12);

        // inline edge score: dot(edge row, u_edge[h]) over this lane's 16 ch
        float pe = e0.x*ue0.x + e0.y*ue0.y + e0.z*ue0.z + e0.w*ue0.w
                 + e1.x*ue1.x + e1.y*ue1.y + e1.z*ue1.z + e1.w*ue1.w
                 + e2.x*ue2.x + e2.y*ue2.y + e2.z*ue2.z + e2.w*ue2.w
                 + e3.x*ue3.x + e3.y*ue3.y + e3.z*ue3.z + e3.w*ue3.w;
        pe += __shfl_xor(pe, 1);
        pe += __shfl_xor(pe, 2);
        pe += __shfl_xor(pe, 4);
        const float se = pe + ce;

        float sc = ss + sd + se;
        sc = sc > 0.f ? sc : 0.2f * sc;              // leaky_relu(0.2)
        float mn = valid ? fmaxf(mrun, sc) : mrun;
        float scale = __expf(mrun - mn);             // ==1 when masked
        float pw = valid ? __expf(sc - mn) : 0.f;
        lsum = lsum * scale + pw;
        mrun = mn;

        float fa[8];
        fa[0]=bf2f(ua.x); fa[1]=bf2f(ua.x>>16); fa[2]=bf2f(ua.y); fa[3]=bf2f(ua.y>>16);
        fa[4]=bf2f(ua.z); fa[5]=bf2f(ua.z>>16); fa[6]=bf2f(ua.w); fa[7]=bf2f(ua.w>>16);

        #pragma unroll
        for (int j = 0; j < 8; ++j) acc[j] = acc[j] * scale + pw * fa[j];
        z[0]  = z[0]  * scale + pw * e0.x;  z[1]  = z[1]  * scale + pw * e0.y;
        z[2]  = z[2]  * scale + pw * e0.z;  z[3]  = z[3]  * scale + pw * e0.w;
        z[4]  = z[4]  * scale + pw * e1.x;  z[5]  = z[5]  * scale + pw * e1.y;
        z[6]  = z[6]  * scale + pw * e1.z;  z[7]  = z[7]  * scale + pw * e1.w;
        z[8]  = z[8]  * scale + pw * e2.x;  z[9]  = z[9]  * scale + pw * e2.y;
        z[10] = z[10] * scale + pw * e2.z;  z[11] = z[11] * scale + pw * e2.w;
        z[12] = z[12] * scale + pw * e3.x;  z[13] = z[13] * scale + pw * e3.y;
        z[14] = z[14] * scale + pw * e3.z;  z[15] = z[15] * scale + pw * e3.w;
    }

    const float inv = lsum > 0.f ? 1.f / lsum : 0.f;

    float4 o0, o1;
    o0.x = acc[0]*inv; o0.y = acc[1]*inv; o0.z = acc[2]*inv; o0.w = acc[3]*inv;
    o1.x = acc[4]*inv; o1.y = acc[5]*inv; o1.z = acc[6]*inv; o1.w = acc[7]*inv;
    float* dst = out + (size_t)n * 512 + l * 8;
    *(float4*)dst = o0;
    *(float4*)(dst + 4) = o1;

    // Z[n][h*128 + sub*16 .. +16] = z*inv (bf16): lane l -> 32B at l*32, coalesced
    union { unsigned int u[8]; uint4 v[2]; } zp;
    #pragma unroll
    for (int i = 0; i < 8; ++i)
        zp.u[i] = (unsigned int)f2bf(z[2*i] * inv)
                | ((unsigned int)f2bf(z[2*i+1] * inv) << 16);
    unsigned short* zdst = Z + (size_t)n * 1024 + l * 16;
    *(uint4*)zdst = zp.v[0];
    *(uint4*)(zdst + 8) = zp.v[1];
}

// ---------------------------------------------------------------------------
// Projection pass: out[n][h*64+j] += (Z[n][h] @ WtB_head) + b_bond.
// Single-shot 64x64 K=128 MFMA tile per block (bond-v2 structure):
// B (head slice of WtB, 16 KB) via global_load_lds, A (Z rows) to registers.
// ---------------------------------------------------------------------------
__global__ __launch_bounds__(256, 4) void proj_kernel(
    const unsigned short* __restrict__ Z, const unsigned short* __restrict__ WtB,
    const float* __restrict__ b_bond, float* __restrict__ out) {
    __shared__ unsigned short Bls[64 * 128];      // 16 KB
    const int t = threadIdx.x;
    const int w = t >> 6, l = t & 63;
    const int h = blockIdx.x & 7;                 // head
    const int mt = blockIdx.x >> 3;               // 0..312

    const int m16 = l & 15, g = l >> 4;
    const int arow = mt * 64 + (w << 4) + m16;    // atom row (may exceed 19999)

    // A: fragment-shaped Z loads (bf16 direct)
    const unsigned short* Zr = Z + (size_t)arow * 1024 + h * 128 + (g << 3);
    uint4 af[4];
    #pragma unroll
    for (int ks = 0; ks < 4; ++ks)
        af[ks] = *(const uint4*)(Zr + (ks << 5));

    // stage B: rows j=0..63 -> WtB[(h*64+j)][128]; 1024 slots of 16B, 16/row.
    // LDS image: slot(nrow,kc) = nrow*16 + (kc ^ (nrow&7)); linear dest.
    {
        #pragma unroll
        for (int i = 0; i < 4; ++i) {
            int s = (w << 8) + (i << 6) + l;      // 0..1023
            int nrow = s >> 4;
            int kc = (s & 15) ^ (nrow & 7);
            const char* src = (const char*)WtB + (size_t)(h * 64 + nrow) * 256 + kc * 16;
            __builtin_amdgcn_global_load_lds(
                (const __attribute__((address_space(1))) void*)src,
                (__attribute__((address_space(3))) void*)((char*)Bls + (((w << 8) + (i << 6)) << 4)),
                16, 0, 0);
        }
    }
    __syncthreads();

    f32x4 acc[4] = {};
    #pragma unroll
    for (int ks = 0; ks < 4; ++ks) {
        short8v a = *(const short8v*)&af[ks];
        #pragma unroll
        for (int nt = 0; nt < 4; ++nt) {
            int nrow = (nt << 4) + m16;
            const short8v b = *(const short8v*)((const char*)Bls +
                ((nrow * 256 + (ks << 6) + (g << 4)) ^ ((nrow & 7) << 4)));
            acc[nt] = __builtin_amdgcn_mfma_f32_16x16x32_bf16(a, b, acc[nt], 0, 0, 0);
        }
    }

    const int rbase = mt * 64 + (w << 4) + (g << 2);
    #pragma unroll
    for (int nt = 0; nt < 4; ++nt) {
        int col = h * 64 + (nt << 4) + m16;
        float bv = b_bond[col];
        #pragma unroll
        for (int r = 0; r < 4; ++r) {
            int grow = rbase + r;
            if (grow < N_ATOMS) {
                float* p = out + (size_t)grow * 512 + col;
                *p = *p + acc[nt][r] + bv;
            }
        }
    }
}

// ---------------------------------------------------------------------------
extern "C" void kernel_launch(void* const* d_in, const int* in_sizes, int n_in,
                              void* d_out, int out_size, void* d_ws, size_t ws_size,
                              hipStream_t stream) {
    const float* x        = (const float*)d_in[0];
    const float* edge     = (const float*)d_in[1];
    const float* W_atom   = (const float*)d_in[2];
    const float* b_atom   = (const float*)d_in[3];
    const float* W_bond   = (const float*)d_in[4];
    const float* b_bond   = (const float*)d_in[5];
    const float* att_src  = (const float*)d_in[6];
    const float* att_dst  = (const float*)d_in[7];
    const float* att_edge = (const float*)d_in[8];
    const int*   a2a      = (const int*)d_in[9];
    const int*   a2b      = (const int*)d_in[10];
    float* out = (float*)d_out;

    char* ws = (char*)d_ws;
    unsigned short* hA   = (unsigned short*)ws;                    // 20,480,000
    unsigned short* Zb   = (unsigned short*)(ws + 20480000);       // 40,960,000
    unsigned short* WtA  = (unsigned short*)(ws + 61440000);       // 262,144
    unsigned short* WtB  = (unsigned short*)(ws + 61702144);       // 131,072
    float* s_src_all     = (float*)(ws + 61833216);                // 640,000
    float* s_dst_all     = (float*)(ws + 62473216);                // 640,000
    float* u_edge        = (float*)(ws + 63113216);                // 4,096
    float* c_edge        = (float*)(ws + 63117312);                // 32

    wt_kernel<<<(512 * 256 + 255) / 256, 256, 0, stream>>>(W_atom, WtA, 256);
    wt_kernel<<<(512 * 128 + 255) / 256, 256, 0, stream>>>(W_bond, WtB, 128);
    uedge_kernel<<<4, 256, 0, stream>>>(W_bond, att_edge, b_bond, u_edge, c_edge);

    // hA = x @ W_atom + b_atom  (bf16)
    gemm_kernel<<<313 * 8, 256, 0, stream>>>(x, WtA, b_atom, hA, N_ATOMS, 256, 313);

    sdots_kernel<<<5000, 256, 0, stream>>>(hA, att_src, att_dst, s_src_all, s_dst_all);

    attn_kernel<<<5000, 256, 0, stream>>>(
        hA, edge, s_src_all, s_dst_all, u_edge, c_edge, a2a, a2b, out, Zb);

    proj_kernel<<<313 * 8, 256, 0, stream>>>(Zb, WtB, b_bond, out);
}

// Round 11
// 165.515 us; speedup vs baseline: 1.1858x; 1.1858x over previous
//
#include <hip/hip_runtime.h>
#include <hip/hip_bf16.h>

#define N_ATOMS 20000
#define N_BONDS 200000
#define MAX_DEG 12
#define IN_DIM 256
#define BOND_DIM 128
#define OUT_DIM 512
#define N_HEADS 8
#define HEAD_DIM 64

typedef __attribute__((ext_vector_type(8))) short short8v;
typedef __attribute__((ext_vector_type(4))) float f32x4;

static __device__ __forceinline__ float bf2f(unsigned int u) {
    union { unsigned int i; float f; } c;
    c.i = (u & 0xffffu) << 16;
    return c.f;
}
static __device__ __forceinline__ unsigned short f2bf(float f) {
    union { float f; unsigned int i; } c;
    c.f = f;
    unsigned int x = c.i;
    x += 0x7fffu + ((x >> 16) & 1u);   // round-to-nearest-even
    return (unsigned short)(x >> 16);
}

// ---------------------------------------------------------------------------
// Wt[n][k] = bf16(W[k][n])  (N fixed 512)
// ---------------------------------------------------------------------------
__global__ void wt_kernel(const float* __restrict__ W, unsigned short* __restrict__ Wt,
                          int K) {
    int id = blockIdx.x * 256 + threadIdx.x;
    if (id >= K * 512) return;
    int n = id / K, k = id % K;
    Wt[id] = f2bf(W[(size_t)k * 512 + n]);
}

// ---------------------------------------------------------------------------
// u_edge[h][c] = sum_k W_bond[c][h*64+k] * att_edge[h][k];  c_edge[h] = b_bond.att_edge
// ---------------------------------------------------------------------------
__global__ void uedge_kernel(const float* __restrict__ Wb, const float* __restrict__ att_edge,
                             const float* __restrict__ b_bond,
                             float* __restrict__ u_edge, float* __restrict__ c_edge) {
    int tid = blockIdx.x * 256 + threadIdx.x;
    if (tid >= 1024) return;
    int h = tid >> 7, c = tid & 127;
    const float* wrow = Wb + (size_t)c * 512 + h * 64;
    const float* ae = att_edge + h * 64;
    float s = 0.f;
    #pragma unroll 8
    for (int k = 0; k < 64; ++k) s += wrow[k] * ae[k];
    u_edge[h * 128 + c] = s;
    if (c == 0) {
        float cs = 0.f;
        const float* bb = b_bond + h * 64;
        for (int k = 0; k < 64; ++k) cs += bb[k] * ae[k];
        c_edge[h] = cs;
    }
}

// ---------------------------------------------------------------------------
// Per-atom score tables from hA: s_src_all[n][h], s_dst_all[n][h].
// ---------------------------------------------------------------------------
__global__ __launch_bounds__(256) void sdots_kernel(
    const unsigned short* __restrict__ hA,
    const float* __restrict__ att_src, const float* __restrict__ att_dst,
    float* __restrict__ s_src_all, float* __restrict__ s_dst_all) {
    const int w = threadIdx.x >> 6, l = threadIdx.x & 63;
    const int n = blockIdx.x * 4 + w;
    if (n >= N_ATOMS) return;
    float4 s0 = *(const float4*)(att_src + l * 8);
    float4 s1 = *(const float4*)(att_src + l * 8 + 4);
    float4 d0 = *(const float4*)(att_dst + l * 8);
    float4 d1 = *(const float4*)(att_dst + l * 8 + 4);
    uint4 u = *(const uint4*)(hA + (size_t)n * 512 + l * 8);
    float fa[8];
    fa[0]=bf2f(u.x); fa[1]=bf2f(u.x>>16); fa[2]=bf2f(u.y); fa[3]=bf2f(u.y>>16);
    fa[4]=bf2f(u.z); fa[5]=bf2f(u.z>>16); fa[6]=bf2f(u.w); fa[7]=bf2f(u.w>>16);
    float ps = fa[0]*s0.x + fa[1]*s0.y + fa[2]*s0.z + fa[3]*s0.w
             + fa[4]*s1.x + fa[5]*s1.y + fa[6]*s1.z + fa[7]*s1.w;
    float pd = fa[0]*d0.x + fa[1]*d0.y + fa[2]*d0.z + fa[3]*d0.w
             + fa[4]*d1.x + fa[5]*d1.y + fa[6]*d1.z + fa[7]*d1.w;
    ps += __shfl_xor(ps, 1); ps += __shfl_xor(ps, 2); ps += __shfl_xor(ps, 4);
    pd += __shfl_xor(pd, 1); pd += __shfl_xor(pd, 2); pd += __shfl_xor(pd, 4);
    if ((l & 7) == 0) {
        s_src_all[n * 8 + (l >> 3)] = ps;
        s_dst_all[n * 8 + (l >> 3)] = pd;
    }
}

// ---------------------------------------------------------------------------
// score_edge[b][h] = edge[b] . u_edge[h] + c_edge[h].  32 bonds/block.
// ---------------------------------------------------------------------------
__global__ __launch_bounds__(256) void escore_kernel(
    const float* __restrict__ edge, const float* __restrict__ u_edge,
    const float* __restrict__ c_edge, float* __restrict__ score_edge) {
    __shared__ float eL[32 * 132];       // padded rows (bank-spread)
    __shared__ float uL[8 * 132];
    __shared__ float cL[8];
    const int t = threadIdx.x;
    const size_t b0 = (size_t)blockIdx.x * 32;
    #pragma unroll
    for (int i = 0; i < 4; ++i) {
        int idx = i * 256 + t;           // f32x4 chunk 0..1023
        int row = idx >> 5, c4 = idx & 31;
        *(float4*)(eL + row * 132 + c4 * 4) = *(const float4*)(edge + b0 * 128 + idx * 4);
    }
    {
        int h = t >> 5, c4 = t & 31;
        *(float4*)(uL + h * 132 + c4 * 4) = *(const float4*)(u_edge + h * 128 + c4 * 4);
    }
    if (t < 8) cL[t] = c_edge[t];
    __syncthreads();
    const int b2 = t >> 3, h = t & 7;
    float s = 0.f;
    #pragma unroll
    for (int c4 = 0; c4 < 32; ++c4) {
        float4 e = *(const float4*)(eL + b2 * 132 + c4 * 4);
        float4 u = *(const float4*)(uL + h * 132 + c4 * 4);
        s += e.x*u.x + e.y*u.y + e.z*u.z + e.w*u.w;
    }
    score_edge[(b0 + b2) * 8 + h] = s + cL[h];
}

// ---------------------------------------------------------------------------
// ATOM GEMM (round-4, proven): tiles 64x64x64, 4 waves, XCD-chunked swizzle.
// ---------------------------------------------------------------------------
__global__ __launch_bounds__(256) void gemm_kernel(
    const float* __restrict__ A, const unsigned short* __restrict__ Wt,
    const float* __restrict__ bias, unsigned short* __restrict__ H,
    int M, int K, int nbm) {
    __shared__ unsigned short Als[64 * 64];
    __shared__ unsigned short Bls[64 * 64];
    const int t = threadIdx.x;
    const int wgid = (blockIdx.x & 7) * nbm + (blockIdx.x >> 3);
    const int bn = wgid & 7;
    const int bm = wgid >> 3;
    const int w = t >> 6;
    const int l = t & 63;

    f32x4 acc[4] = {};

    const int nk = K >> 6;
    for (int kk = 0; kk < nk; ++kk) {
        #pragma unroll
        for (int i = 0; i < 2; ++i) {
            int c = t + i * 256;
            int row = c >> 3;
            int k8 = (c & 7) << 3;
            int grow = (bm << 6) + row;
            float f[8];
            if (grow < M) {
                const float* src = A + (size_t)grow * K + (kk << 6) + k8;
                float4 v0 = *(const float4*)src;
                float4 v1 = *(const float4*)(src + 4);
                f[0] = v0.x; f[1] = v0.y; f[2] = v0.z; f[3] = v0.w;
                f[4] = v1.x; f[5] = v1.y; f[6] = v1.z; f[7] = v1.w;
            } else {
                #pragma unroll
                for (int j = 0; j < 8; ++j) f[j] = 0.f;
            }
            union { unsigned short us[8]; uint4 v; } pk;
            #pragma unroll
            for (int j = 0; j < 8; ++j) pk.us[j] = f2bf(f[j]);
            int byte = ((row << 7) + (k8 << 1)) ^ ((row & 7) << 4);
            *(uint4*)((char*)Als + byte) = pk.v;
        }
        #pragma unroll
        for (int i = 0; i < 2; ++i) {
            int c = t + i * 256;
            int row = c >> 3;
            int k8 = (c & 7) << 3;
            int gn = (bn << 6) + row;
            uint4 v = *(const uint4*)(Wt + (size_t)gn * K + (kk << 6) + k8);
            int byte = ((row << 7) + (k8 << 1)) ^ ((row & 7) << 4);
            *(uint4*)((char*)Bls + byte) = v;
        }
        __syncthreads();

        const int m = l & 15;
        const int kg = (l >> 4) << 3;
        #pragma unroll
        for (int ks = 0; ks < 2; ++ks) {
            int kcol = (ks << 5) + kg;
            int arow = (w << 4) + m;
            short8v a = *(short8v*)((char*)Als +
                (((arow << 7) + (kcol << 1)) ^ ((arow & 7) << 4)));
            #pragma unroll
            for (int nt = 0; nt < 4; ++nt) {
                int nrow = (nt << 4) + m;
                short8v b = *(short8v*)((char*)Bls +
                    (((nrow << 7) + (kcol << 1)) ^ ((nrow & 7) << 4)));
                acc[nt] = __builtin_amdgcn_mfma_f32_16x16x32_bf16(a, b, acc[nt], 0, 0, 0);
            }
        }
        __syncthreads();
    }

    const int m = l & 15;
    const int rbase = (bm << 6) + (w << 4) + ((l >> 4) << 2);
    #pragma unroll
    for (int nt = 0; nt < 4; ++nt) {
        int col = (bn << 6) + (nt << 4) + m;
        float bv = bias[col];
        #pragma unroll
        for (int r = 0; r < 4; ++r) {
            int grow = rbase + r;
            if (grow < M) H[(size_t)grow * 512 + col] = f2bf(acc[nt][r] + bv);
        }
    }
}

// ---------------------------------------------------------------------------
// Fused attention v4: per-lane softmax for OWN head (h = l>>3), with the 12
// neighbors split into TWO independent online-softmax chains (d=0..5 and
// d=6..11) interleaved in the same lane -> 2x ILP, half the serial
// fmax->exp->rescale chain. Chains merged exactly at the end.
// Lane l: atom-value channels l*8..+8, z-part edge channels (l&7)*16..+16.
// ---------------------------------------------------------------------------
__global__ __launch_bounds__(256) void attn_kernel(
    const unsigned short* __restrict__ hA,
    const float* __restrict__ edge,
    const float* __restrict__ s_src_all,
    const float* __restrict__ s_dst_all,
    const float* __restrict__ score_edge,
    const int* __restrict__ a2a,
    const int* __restrict__ a2b,
    float* __restrict__ out,
    unsigned short* __restrict__ Z) {
    const int w = threadIdx.x >> 6;
    const int l = threadIdx.x & 63;
    const int n = blockIdx.x * 4 + w;
    if (n >= N_ATOMS) return;
    const int h = l >> 3, sub = l & 7;

    const float ss = s_src_all[n * 8 + h];

    float mA = -1e30f, lsA = 0.f, mB = -1e30f, lsB = 0.f;
    float aA[8], aB[8], zA[16], zB[16];
    #pragma unroll
    for (int j = 0; j < 8; ++j) { aA[j] = 0.f; aB[j] = 0.f; }
    #pragma unroll
    for (int j = 0; j < 16; ++j) { zA[j] = 0.f; zB[j] = 0.f; }

    const int* pa = a2a + n * MAX_DEG;
    const int* pb = a2b + n * MAX_DEG;

    for (int d = 0; d < 6; ++d) {
        // ---- issue both chains' index + gather loads up front ----
        const int ia0 = pa[d],     ib0 = pb[d];
        const int ia1 = pa[d + 6], ib1 = pb[d + 6];
        const bool v0 = (ia0 != 0), v1 = (ia1 != 0);

        const float sd0 = s_dst_all[ia0 * 8 + h];
        const float se0 = score_edge[ib0 * 8 + h];
        const float sd1 = s_dst_all[ia1 * 8 + h];
        const float se1 = score_edge[ib1 * 8 + h];
        uint4 ua0 = *(const uint4*)(hA + (size_t)ia0 * 512 + l * 8);
        uint4 ua1 = *(const uint4*)(hA + (size_t)ia1 * 512 + l * 8);
        const float* ep0 = edge + (size_t)ib0 * 128 + sub * 16;
        const float* ep1 = edge + (size_t)ib1 * 128 + sub * 16;
        float4 e00 = *(const float4*)(ep0);
        float4 e01 = *(const float4*)(ep0 + 4);
        float4 e02 = *(const float4*)(ep0 + 8);
        float4 e03 = *(const float4*)(ep0 + 12);
        float4 e10 = *(const float4*)(ep1);
        float4 e11 = *(const float4*)(ep1 + 4);
        float4 e12 = *(const float4*)(ep1 + 8);
        float4 e13 = *(const float4*)(ep1 + 12);

        // ---- chain A softmax step ----
        float sc0 = ss + sd0 + se0;
        sc0 = sc0 > 0.f ? sc0 : 0.2f * sc0;
        float mn0 = v0 ? fmaxf(mA, sc0) : mA;
        float scale0 = __expf(mA - mn0);
        float pw0 = v0 ? __expf(sc0 - mn0) : 0.f;
        lsA = lsA * scale0 + pw0;
        mA = mn0;
        // ---- chain B softmax step (independent -> overlaps A) ----
        float sc1 = ss + sd1 + se1;
        sc1 = sc1 > 0.f ? sc1 : 0.2f * sc1;
        float mn1 = v1 ? fmaxf(mB, sc1) : mB;
        float scale1 = __expf(mB - mn1);
        float pw1 = v1 ? __expf(sc1 - mn1) : 0.f;
        lsB = lsB * scale1 + pw1;
        mB = mn1;

        float fa0[8], fa1[8];
        fa0[0]=bf2f(ua0.x); fa0[1]=bf2f(ua0.x>>16); fa0[2]=bf2f(ua0.y); fa0[3]=bf2f(ua0.y>>16);
        fa0[4]=bf2f(ua0.z); fa0[5]=bf2f(ua0.z>>16); fa0[6]=bf2f(ua0.w); fa0[7]=bf2f(ua0.w>>16);
        fa1[0]=bf2f(ua1.x); fa1[1]=bf2f(ua1.x>>16); fa1[2]=bf2f(ua1.y); fa1[3]=bf2f(ua1.y>>16);
        fa1[4]=bf2f(ua1.z); fa1[5]=bf2f(ua1.z>>16); fa1[6]=bf2f(ua1.w); fa1[7]=bf2f(ua1.w>>16);

        #pragma unroll
        for (int j = 0; j < 8; ++j) {
            aA[j] = aA[j] * scale0 + pw0 * fa0[j];
            aB[j] = aB[j] * scale1 + pw1 * fa1[j];
        }
        zA[0] = zA[0]*scale0 + pw0*e00.x;  zB[0] = zB[0]*scale1 + pw1*e10.x;
        zA[1] = zA[1]*scale0 + pw0*e00.y;  zB[1] = zB[1]*scale1 + pw1*e10.y;
        zA[2] = zA[2]*scale0 + pw0*e00.z;  zB[2] = zB[2]*scale1 + pw1*e10.z;
        zA[3] = zA[3]*scale0 + pw0*e00.w;  zB[3] = zB[3]*scale1 + pw1*e10.w;
        zA[4] = zA[4]*scale0 + pw0*e01.x;  zB[4] = zB[4]*scale1 + pw1*e11.x;
        zA[5] = zA[5]*scale0 + pw0*e01.y;  zB[5] = zB[5]*scale1 + pw1*e11.y;
        zA[6] = zA[6]*scale0 + pw0*e01.z;  zB[6] = zB[6]*scale1 + pw1*e11.z;
        zA[7] = zA[7]*scale0 + pw0*e01.w;  zB[7] = zB[7]*scale1 + pw1*e11.w;
        zA[8] = zA[8]*scale0 + pw0*e02.x;  zB[8] = zB[8]*scale1 + pw1*e12.x;
        zA[9] = zA[9]*scale0 + pw0*e02.y;  zB[9] = zB[9]*scale1 + pw1*e12.y;
        zA[10]= zA[10]*scale0 + pw0*e02.z; zB[10]= zB[10]*scale1 + pw1*e12.z;
        zA[11]= zA[11]*scale0 + pw0*e02.w; zB[11]= zB[11]*scale1 + pw1*e12.w;
        zA[12]= zA[12]*scale0 + pw0*e03.x; zB[12]= zB[12]*scale1 + pw1*e13.x;
        zA[13]= zA[13]*scale0 + pw0*e03.y; zB[13]= zB[13]*scale1 + pw1*e13.y;
        zA[14]= zA[14]*scale0 + pw0*e03.z; zB[14]= zB[14]*scale1 + pw1*e13.z;
        zA[15]= zA[15]*scale0 + pw0*e03.w; zB[15]= zB[15]*scale1 + pw1*e13.w;
    }

    // ---- exact merge of the two chains ----
    const float m = fmaxf(mA, mB);
    const float sA = __expf(mA - m);
    const float sB = __expf(mB - m);
    const float lsum = lsA * sA + lsB * sB;
    const float inv = lsum > 0.f ? 1.f / lsum : 0.f;
    const float fA = sA * inv, fB = sB * inv;

    float4 o0, o1;
    o0.x = aA[0]*fA + aB[0]*fB;  o0.y = aA[1]*fA + aB[1]*fB;
    o0.z = aA[2]*fA + aB[2]*fB;  o0.w = aA[3]*fA + aB[3]*fB;
    o1.x = aA[4]*fA + aB[4]*fB;  o1.y = aA[5]*fA + aB[5]*fB;
    o1.z = aA[6]*fA + aB[6]*fB;  o1.w = aA[7]*fA + aB[7]*fB;
    float* dst = out + (size_t)n * 512 + l * 8;
    *(float4*)dst = o0;
    *(float4*)(dst + 4) = o1;

    // Z[n][h*128 + sub*16 .. +16] bf16: lane l -> 32B at l*32, coalesced
    union { unsigned int u[8]; uint4 v[2]; } zp;
    #pragma unroll
    for (int i = 0; i < 8; ++i) {
        float z0 = zA[2*i]   * fA + zB[2*i]   * fB;
        float z1 = zA[2*i+1] * fA + zB[2*i+1] * fB;
        zp.u[i] = (unsigned int)f2bf(z0) | ((unsigned int)f2bf(z1) << 16);
    }
    unsigned short* zdst = Z + (size_t)n * 1024 + l * 16;
    *(uint4*)zdst = zp.v[0];
    *(uint4*)(zdst + 8) = zp.v[1];
}

// ---------------------------------------------------------------------------
// Projection pass: out[n][h*64+j] += (Z[n][h] @ WtB_head) + b_bond.
// Single-shot 64x64 K=128 MFMA tile per block (bond-v2 structure):
// B (head slice of WtB, 16 KB) via global_load_lds, A (Z rows) to registers.
// ---------------------------------------------------------------------------
__global__ __launch_bounds__(256, 4) void proj_kernel(
    const unsigned short* __restrict__ Z, const unsigned short* __restrict__ WtB,
    const float* __restrict__ b_bond, float* __restrict__ out) {
    __shared__ unsigned short Bls[64 * 128];      // 16 KB
    const int t = threadIdx.x;
    const int w = t >> 6, l = t & 63;
    const int h = blockIdx.x & 7;                 // head
    const int mt = blockIdx.x >> 3;               // 0..312

    const int m16 = l & 15, g = l >> 4;
    const int arow = mt * 64 + (w << 4) + m16;    // atom row (may exceed 19999)

    // A: fragment-shaped Z loads (bf16 direct)
    const unsigned short* Zr = Z + (size_t)arow * 1024 + h * 128 + (g << 3);
    uint4 af[4];
    #pragma unroll
    for (int ks = 0; ks < 4; ++ks)
        af[ks] = *(const uint4*)(Zr + (ks << 5));

    // stage B: rows j=0..63 -> WtB[(h*64+j)][128]; 1024 slots of 16B, 16/row.
    // LDS image: slot(nrow,kc) = nrow*16 + (kc ^ (nrow&7)); linear dest.
    {
        #pragma unroll
        for (int i = 0; i < 4; ++i) {
            int s = (w << 8) + (i << 6) + l;      // 0..1023
            int nrow = s >> 4;
            int kc = (s & 15) ^ (nrow & 7);
            const char* src = (const char*)WtB + (size_t)(h * 64 + nrow) * 256 + kc * 16;
            __builtin_amdgcn_global_load_lds(
                (const __attribute__((address_space(1))) void*)src,
                (__attribute__((address_space(3))) void*)((char*)Bls + (((w << 8) + (i << 6)) << 4)),
                16, 0, 0);
        }
    }
    __syncthreads();

    f32x4 acc[4] = {};
    #pragma unroll
    for (int ks = 0; ks < 4; ++ks) {
        short8v a = *(const short8v*)&af[ks];
        #pragma unroll
        for (int nt = 0; nt < 4; ++nt) {
            int nrow = (nt << 4) + m16;
            const short8v b = *(const short8v*)((const char*)Bls +
                ((nrow * 256 + (ks << 6) + (g << 4)) ^ ((nrow & 7) << 4)));
            acc[nt] = __builtin_amdgcn_mfma_f32_16x16x32_bf16(a, b, acc[nt], 0, 0, 0);
        }
    }

    const int rbase = mt * 64 + (w << 4) + (g << 2);
    #pragma unroll
    for (int nt = 0; nt < 4; ++nt) {
        int col = h * 64 + (nt << 4) + m16;
        float bv = b_bond[col];
        #pragma unroll
        for (int r = 0; r < 4; ++r) {
            int grow = rbase + r;
            if (grow < N_ATOMS) {
                float* p = out + (size_t)grow * 512 + col;
                *p = *p + acc[nt][r] + bv;
            }
        }
    }
}

// ---------------------------------------------------------------------------
extern "C" void kernel_launch(void* const* d_in, const int* in_sizes, int n_in,
                              void* d_out, int out_size, void* d_ws, size_t ws_size,
                              hipStream_t stream) {
    const float* x        = (const float*)d_in[0];
    const float* edge     = (const float*)d_in[1];
    const float* W_atom   = (const float*)d_in[2];
    const float* b_atom   = (const float*)d_in[3];
    const float* W_bond   = (const float*)d_in[4];
    const float* b_bond   = (const float*)d_in[5];
    const float* att_src  = (const float*)d_in[6];
    const float* att_dst  = (const float*)d_in[7];
    const float* att_edge = (const float*)d_in[8];
    const int*   a2a      = (const int*)d_in[9];
    const int*   a2b      = (const int*)d_in[10];
    float* out = (float*)d_out;

    char* ws = (char*)d_ws;
    unsigned short* hA   = (unsigned short*)ws;                    // 20,480,000
    unsigned short* Zb   = (unsigned short*)(ws + 20480000);       // 40,960,000
    unsigned short* WtA  = (unsigned short*)(ws + 61440000);       // 262,144
    unsigned short* WtB  = (unsigned short*)(ws + 61702144);       // 131,072
    float* s_src_all     = (float*)(ws + 61833216);                // 640,000
    float* s_dst_all     = (float*)(ws + 62473216);                // 640,000
    float* score_edge    = (float*)(ws + 63113216);                // 6,400,000
    float* u_edge        = (float*)(ws + 69513216);                // 4,096
    float* c_edge        = (float*)(ws + 69517312);                // 32

    wt_kernel<<<(512 * 256 + 255) / 256, 256, 0, stream>>>(W_atom, WtA, 256);
    wt_kernel<<<(512 * 128 + 255) / 256, 256, 0, stream>>>(W_bond, WtB, 128);
    uedge_kernel<<<4, 256, 0, stream>>>(W_bond, att_edge, b_bond, u_edge, c_edge);

    // hA = x @ W_atom + b_atom  (bf16)
    gemm_kernel<<<313 * 8, 256, 0, stream>>>(x, WtA, b_atom, hA, N_ATOMS, 256, 313);

    sdots_kernel<<<5000, 256, 0, stream>>>(hA, att_src, att_dst, s_src_all, s_dst_all);
    escore_kernel<<<6250, 256, 0, stream>>>(edge, u_edge, c_edge, score_edge);

    attn_kernel<<<5000, 256, 0, stream>>>(
        hA, edge, s_src_all, s_dst_all, score_edge, a2a, a2b, out, Zb);

    proj_kernel<<<313 * 8, 256, 0, stream>>>(Zb, WtB, b_bond, out);
}

// Round 12
// 155.439 us; speedup vs baseline: 1.2627x; 1.0648x over previous
//
#include <hip/hip_runtime.h>
#include <hip/hip_bf16.h>

#define N_ATOMS 20000
#define N_BONDS 200000
#define MAX_DEG 12
#define IN_DIM 256
#define BOND_DIM 128
#define OUT_DIM 512
#define N_HEADS 8
#define HEAD_DIM 64

typedef __attribute__((ext_vector_type(8))) short short8v;
typedef __attribute__((ext_vector_type(4))) float f32x4;

static __device__ __forceinline__ float bf2f(unsigned int u) {
    union { unsigned int i; float f; } c;
    c.i = (u & 0xffffu) << 16;
    return c.f;
}
static __device__ __forceinline__ unsigned short f2bf(float f) {
    union { float f; unsigned int i; } c;
    c.f = f;
    unsigned int x = c.i;
    x += 0x7fffu + ((x >> 16) & 1u);   // round-to-nearest-even
    return (unsigned short)(x >> 16);
}

// ---------------------------------------------------------------------------
// PREP (fused): WtA (blocks 0..511), WtB (512..767), u_edge/c_edge (768..771)
// ---------------------------------------------------------------------------
__global__ __launch_bounds__(256) void prep_kernel(
    const float* __restrict__ W_atom, const float* __restrict__ W_bond,
    const float* __restrict__ att_edge, const float* __restrict__ b_bond,
    unsigned short* __restrict__ WtA, unsigned short* __restrict__ WtB,
    float* __restrict__ u_edge, float* __restrict__ c_edge) {
    const int b = blockIdx.x;
    if (b < 512) {                      // WtA[n][k] = bf16(W_atom[k][n]), K=256
        int id = b * 256 + threadIdx.x;
        int n = id >> 8, k = id & 255;
        WtA[id] = f2bf(W_atom[(size_t)k * 512 + n]);
    } else if (b < 768) {               // WtB[n][k] = bf16(W_bond[k][n]), K=128
        int id = (b - 512) * 256 + threadIdx.x;
        int n = id >> 7, k = id & 127;
        WtB[id] = f2bf(W_bond[(size_t)k * 512 + n]);
    } else {                            // u_edge / c_edge
        int tid = (b - 768) * 256 + threadIdx.x;
        if (tid >= 1024) return;
        int h = tid >> 7, c = tid & 127;
        const float* wrow = W_bond + (size_t)c * 512 + h * 64;
        const float* ae = att_edge + h * 64;
        float s = 0.f;
        #pragma unroll 8
        for (int k = 0; k < 64; ++k) s += wrow[k] * ae[k];
        u_edge[h * 128 + c] = s;
        if (c == 0) {
            float cs = 0.f;
            const float* bb = b_bond + h * 64;
            for (int k = 0; k < 64; ++k) cs += bb[k] * ae[k];
            c_edge[h] = cs;
        }
    }
}

// ---------------------------------------------------------------------------
// STAGE1 (fused): blocks 0..2503 = atom GEMM (round-4 proven, XCD swizzle);
// blocks 2504..8753 = escore. Union LDS (21152 B).
// ---------------------------------------------------------------------------
__global__ __launch_bounds__(256) void stage1_kernel(
    const float* __restrict__ x, const unsigned short* __restrict__ WtA,
    const float* __restrict__ b_atom, unsigned short* __restrict__ hA,
    const float* __restrict__ edge, const float* __restrict__ u_edge,
    const float* __restrict__ c_edge, float* __restrict__ score_edge) {
    __shared__ __align__(16) unsigned char smem[21152];
    const int t = threadIdx.x;

    if (blockIdx.x < 2504) {
        // ================= ATOM GEMM path (M=20000, K=256, nbm=313) ========
        unsigned short* Als = (unsigned short*)smem;
        unsigned short* Bls = (unsigned short*)(smem + 8192);
        const int wgid = (blockIdx.x & 7) * 313 + (blockIdx.x >> 3);
        const int bn = wgid & 7;
        const int bm = wgid >> 3;
        const int w = t >> 6;
        const int l = t & 63;

        f32x4 acc[4] = {};

        for (int kk = 0; kk < 4; ++kk) {
            #pragma unroll
            for (int i = 0; i < 2; ++i) {
                int c = t + i * 256;
                int row = c >> 3;
                int k8 = (c & 7) << 3;
                int grow = (bm << 6) + row;
                float f[8];
                if (grow < N_ATOMS) {
                    const float* src = x + (size_t)grow * 256 + (kk << 6) + k8;
                    float4 v0 = *(const float4*)src;
                    float4 v1 = *(const float4*)(src + 4);
                    f[0] = v0.x; f[1] = v0.y; f[2] = v0.z; f[3] = v0.w;
                    f[4] = v1.x; f[5] = v1.y; f[6] = v1.z; f[7] = v1.w;
                } else {
                    #pragma unroll
                    for (int j = 0; j < 8; ++j) f[j] = 0.f;
                }
                union { unsigned short us[8]; uint4 v; } pk;
                #pragma unroll
                for (int j = 0; j < 8; ++j) pk.us[j] = f2bf(f[j]);
                int byte = ((row << 7) + (k8 << 1)) ^ ((row & 7) << 4);
                *(uint4*)((char*)Als + byte) = pk.v;
            }
            #pragma unroll
            for (int i = 0; i < 2; ++i) {
                int c = t + i * 256;
                int row = c >> 3;
                int k8 = (c & 7) << 3;
                int gn = (bn << 6) + row;
                uint4 v = *(const uint4*)(WtA + (size_t)gn * 256 + (kk << 6) + k8);
                int byte = ((row << 7) + (k8 << 1)) ^ ((row & 7) << 4);
                *(uint4*)((char*)Bls + byte) = v;
            }
            __syncthreads();

            const int m = l & 15;
            const int kg = (l >> 4) << 3;
            #pragma unroll
            for (int ks = 0; ks < 2; ++ks) {
                int kcol = (ks << 5) + kg;
                int arow = (w << 4) + m;
                short8v a = *(short8v*)((char*)Als +
                    (((arow << 7) + (kcol << 1)) ^ ((arow & 7) << 4)));
                #pragma unroll
                for (int nt = 0; nt < 4; ++nt) {
                    int nrow = (nt << 4) + m;
                    short8v bfr = *(short8v*)((char*)Bls +
                        (((nrow << 7) + (kcol << 1)) ^ ((nrow & 7) << 4)));
                    acc[nt] = __builtin_amdgcn_mfma_f32_16x16x32_bf16(a, bfr, acc[nt], 0, 0, 0);
                }
            }
            __syncthreads();
        }

        const int m = l & 15;
        const int rbase = (bm << 6) + (w << 4) + ((l >> 4) << 2);
        #pragma unroll
        for (int nt = 0; nt < 4; ++nt) {
            int col = (bn << 6) + (nt << 4) + m;
            float bv = b_atom[col];
            #pragma unroll
            for (int r = 0; r < 4; ++r) {
                int grow = rbase + r;
                if (grow < N_ATOMS) hA[(size_t)grow * 512 + col] = f2bf(acc[nt][r] + bv);
            }
        }
    } else {
        // ================= ESCORE path: 32 bonds/block =====================
        float* eL = (float*)smem;                 // 32*132 floats
        float* uL = (float*)(smem + 16896);       // 8*132 floats
        float* cL = (float*)(smem + 21120);       // 8 floats
        const size_t b0 = (size_t)(blockIdx.x - 2504) * 32;
        #pragma unroll
        for (int i = 0; i < 4; ++i) {
            int idx = i * 256 + t;
            int row = idx >> 5, c4 = idx & 31;
            *(float4*)(eL + row * 132 + c4 * 4) = *(const float4*)(edge + b0 * 128 + idx * 4);
        }
        {
            int h = t >> 5, c4 = t & 31;
            *(float4*)(uL + h * 132 + c4 * 4) = *(const float4*)(u_edge + h * 128 + c4 * 4);
        }
        if (t < 8) cL[t] = c_edge[t];
        __syncthreads();
        const int b2 = t >> 3, h = t & 7;
        float s = 0.f;
        #pragma unroll
        for (int c4 = 0; c4 < 32; ++c4) {
            float4 e = *(const float4*)(eL + b2 * 132 + c4 * 4);
            float4 u = *(const float4*)(uL + h * 132 + c4 * 4);
            s += e.x*u.x + e.y*u.y + e.z*u.z + e.w*u.w;
        }
        score_edge[(b0 + b2) * 8 + h] = s + cL[h];
    }
}

// ---------------------------------------------------------------------------
// Per-atom score tables from hA: s_src_all[n][h], s_dst_all[n][h].
// ---------------------------------------------------------------------------
__global__ __launch_bounds__(256) void sdots_kernel(
    const unsigned short* __restrict__ hA,
    const float* __restrict__ att_src, const float* __restrict__ att_dst,
    float* __restrict__ s_src_all, float* __restrict__ s_dst_all) {
    const int w = threadIdx.x >> 6, l = threadIdx.x & 63;
    const int n = blockIdx.x * 4 + w;
    if (n >= N_ATOMS) return;
    float4 s0 = *(const float4*)(att_src + l * 8);
    float4 s1 = *(const float4*)(att_src + l * 8 + 4);
    float4 d0 = *(const float4*)(att_dst + l * 8);
    float4 d1 = *(const float4*)(att_dst + l * 8 + 4);
    uint4 u = *(const uint4*)(hA + (size_t)n * 512 + l * 8);
    float fa[8];
    fa[0]=bf2f(u.x); fa[1]=bf2f(u.x>>16); fa[2]=bf2f(u.y); fa[3]=bf2f(u.y>>16);
    fa[4]=bf2f(u.z); fa[5]=bf2f(u.z>>16); fa[6]=bf2f(u.w); fa[7]=bf2f(u.w>>16);
    float ps = fa[0]*s0.x + fa[1]*s0.y + fa[2]*s0.z + fa[3]*s0.w
             + fa[4]*s1.x + fa[5]*s1.y + fa[6]*s1.z + fa[7]*s1.w;
    float pd = fa[0]*d0.x + fa[1]*d0.y + fa[2]*d0.z + fa[3]*d0.w
             + fa[4]*d1.x + fa[5]*d1.y + fa[6]*d1.z + fa[7]*d1.w;
    ps += __shfl_xor(ps, 1); ps += __shfl_xor(ps, 2); ps += __shfl_xor(ps, 4);
    pd += __shfl_xor(pd, 1); pd += __shfl_xor(pd, 2); pd += __shfl_xor(pd, 4);
    if ((l & 7) == 0) {
        s_src_all[n * 8 + (l >> 3)] = ps;
        s_dst_all[n * 8 + (l >> 3)] = pd;
    }
}

// ---------------------------------------------------------------------------
// Fused attention v5: TWO-PHASE softmax, no serial chain.
// Phase 1: gather all 24 score operands (independent), 12 scores in regs,
// tree max, 12 independent exps (masked -> -3e38 sentinel, exp underflows
// to exactly 0), sum. Phase 2: 12 independent weighted-accumulate iterations
// (no rescale, no loop-carried chain). Lane l: head h=l>>3, atom-value
// channels l*8..+8, z-part edge channels (l&7)*16..+16.
// ---------------------------------------------------------------------------
__global__ __launch_bounds__(256) void attn_kernel(
    const unsigned short* __restrict__ hA,
    const float* __restrict__ edge,
    const float* __restrict__ s_src_all,
    const float* __restrict__ s_dst_all,
    const float* __restrict__ score_edge,
    const int* __restrict__ a2a,
    const int* __restrict__ a2b,
    float* __restrict__ out,
    unsigned short* __restrict__ Z) {
    const int w = threadIdx.x >> 6;
    const int l = threadIdx.x & 63;
    const int n = blockIdx.x * 4 + w;
    if (n >= N_ATOMS) return;
    const int h = l >> 3, sub = l & 7;

    const float ss = s_src_all[n * 8 + h];
    const int* pa = a2a + n * MAX_DEG;
    const int* pb = a2b + n * MAX_DEG;

    // ---- phase 1: all score gathers independent; exact softmax in regs ----
    float pw[12];
    #pragma unroll
    for (int d = 0; d < 12; ++d) {
        const int iad = pa[d];
        const int ibd = pb[d];
        float sd = s_dst_all[iad * 8 + h];
        float se = score_edge[ibd * 8 + h];
        float s = ss + sd + se;
        s = s > 0.f ? s : 0.2f * s;                 // leaky_relu(0.2)
        pw[d] = (iad != 0) ? s : -3e38f;            // sentinel for masked
    }
    float mx = fmaxf(
        fmaxf(fmaxf(fmaxf(pw[0], pw[1]), fmaxf(pw[2], pw[3])),
              fmaxf(fmaxf(pw[4], pw[5]), fmaxf(pw[6], pw[7]))),
        fmaxf(fmaxf(pw[8], pw[9]), fmaxf(pw[10], pw[11])));
    float lsum = 0.f;
    #pragma unroll
    for (int d = 0; d < 12; ++d) {
        pw[d] = __expf(pw[d] - mx);                 // masked: exp(-huge) = 0
        lsum += pw[d];
    }
    const float inv = lsum > 0.f ? 1.f / lsum : 0.f;

    // ---- phase 2: independent weighted accumulation (no chain) ----
    float acc[8], z[16];
    #pragma unroll
    for (int j = 0; j < 8; ++j) acc[j] = 0.f;
    #pragma unroll
    for (int j = 0; j < 16; ++j) z[j] = 0.f;

    #pragma unroll 2
    for (int d = 0; d < 12; ++d) {
        const int iad = pa[d];
        const int ibd = pb[d];
        const float p = pw[d];
        uint4 ua = *(const uint4*)(hA + (size_t)iad * 512 + l * 8);
        const float* ep = edge + (size_t)ibd * 128 + sub * 16;
        float4 e0 = *(const float4*)(ep);
        float4 e1 = *(const float4*)(ep + 4);
        float4 e2 = *(const float4*)(ep + 8);
        float4 e3 = *(const float4*)(ep + 12);

        float fa[8];
        fa[0]=bf2f(ua.x); fa[1]=bf2f(ua.x>>16); fa[2]=bf2f(ua.y); fa[3]=bf2f(ua.y>>16);
        fa[4]=bf2f(ua.z); fa[5]=bf2f(ua.z>>16); fa[6]=bf2f(ua.w); fa[7]=bf2f(ua.w>>16);

        #pragma unroll
        for (int j = 0; j < 8; ++j) acc[j] += p * fa[j];
        z[0]  += p * e0.x;  z[1]  += p * e0.y;  z[2]  += p * e0.z;  z[3]  += p * e0.w;
        z[4]  += p * e1.x;  z[5]  += p * e1.y;  z[6]  += p * e1.z;  z[7]  += p * e1.w;
        z[8]  += p * e2.x;  z[9]  += p * e2.y;  z[10] += p * e2.z;  z[11] += p * e2.w;
        z[12] += p * e3.x;  z[13] += p * e3.y;  z[14] += p * e3.z;  z[15] += p * e3.w;
    }

    float4 o0, o1;
    o0.x = acc[0]*inv; o0.y = acc[1]*inv; o0.z = acc[2]*inv; o0.w = acc[3]*inv;
    o1.x = acc[4]*inv; o1.y = acc[5]*inv; o1.z = acc[6]*inv; o1.w = acc[7]*inv;
    float* dst = out + (size_t)n * 512 + l * 8;
    *(float4*)dst = o0;
    *(float4*)(dst + 4) = o1;

    // Z[n][h*128 + sub*16 .. +16] bf16: lane l -> 32B at l*32, coalesced
    union { unsigned int u[8]; uint4 v[2]; } zp;
    #pragma unroll
    for (int i = 0; i < 8; ++i)
        zp.u[i] = (unsigned int)f2bf(z[2*i] * inv)
                | ((unsigned int)f2bf(z[2*i+1] * inv) << 16);
    unsigned short* zdst = Z + (size_t)n * 1024 + l * 16;
    *(uint4*)zdst = zp.v[0];
    *(uint4*)(zdst + 8) = zp.v[1];
}

// ---------------------------------------------------------------------------
// Projection pass: out[n][h*64+j] += (Z[n][h] @ WtB_head) + b_bond.
// ---------------------------------------------------------------------------
__global__ __launch_bounds__(256, 4) void proj_kernel(
    const unsigned short* __restrict__ Z, const unsigned short* __restrict__ WtB,
    const float* __restrict__ b_bond, float* __restrict__ out) {
    __shared__ unsigned short Bls[64 * 128];      // 16 KB
    const int t = threadIdx.x;
    const int w = t >> 6, l = t & 63;
    const int h = blockIdx.x & 7;                 // head
    const int mt = blockIdx.x >> 3;               // 0..312

    const int m16 = l & 15, g = l >> 4;
    const int arow = mt * 64 + (w << 4) + m16;

    const unsigned short* Zr = Z + (size_t)arow * 1024 + h * 128 + (g << 3);
    uint4 af[4];
    #pragma unroll
    for (int ks = 0; ks < 4; ++ks)
        af[ks] = *(const uint4*)(Zr + (ks << 5));

    {
        #pragma unroll
        for (int i = 0; i < 4; ++i) {
            int s = (w << 8) + (i << 6) + l;      // 0..1023
            int nrow = s >> 4;
            int kc = (s & 15) ^ (nrow & 7);
            const char* src = (const char*)WtB + (size_t)(h * 64 + nrow) * 256 + kc * 16;
            __builtin_amdgcn_global_load_lds(
                (const __attribute__((address_space(1))) void*)src,
                (__attribute__((address_space(3))) void*)((char*)Bls + (((w << 8) + (i << 6)) << 4)),
                16, 0, 0);
        }
    }
    __syncthreads();

    f32x4 acc[4] = {};
    #pragma unroll
    for (int ks = 0; ks < 4; ++ks) {
        short8v a = *(const short8v*)&af[ks];
        #pragma unroll
        for (int nt = 0; nt < 4; ++nt) {
            int nrow = (nt << 4) + m16;
            const short8v b = *(const short8v*)((const char*)Bls +
                ((nrow * 256 + (ks << 6) + (g << 4)) ^ ((nrow & 7) << 4)));
            acc[nt] = __builtin_amdgcn_mfma_f32_16x16x32_bf16(a, b, acc[nt], 0, 0, 0);
        }
    }

    const int rbase = mt * 64 + (w << 4) + (g << 2);
    #pragma unroll
    for (int nt = 0; nt < 4; ++nt) {
        int col = h * 64 + (nt << 4) + m16;
        float bv = b_bond[col];
        #pragma unroll
        for (int r = 0; r < 4; ++r) {
            int grow = rbase + r;
            if (grow < N_ATOMS) {
                float* p = out + (size_t)grow * 512 + col;
                *p = *p + acc[nt][r] + bv;
            }
        }
    }
}

// ---------------------------------------------------------------------------
extern "C" void kernel_launch(void* const* d_in, const int* in_sizes, int n_in,
                              void* d_out, int out_size, void* d_ws, size_t ws_size,
                              hipStream_t stream) {
    const float* x        = (const float*)d_in[0];
    const float* edge     = (const float*)d_in[1];
    const float* W_atom   = (const float*)d_in[2];
    const float* b_atom   = (const float*)d_in[3];
    const float* W_bond   = (const float*)d_in[4];
    const float* b_bond   = (const float*)d_in[5];
    const float* att_src  = (const float*)d_in[6];
    const float* att_dst  = (const float*)d_in[7];
    const float* att_edge = (const float*)d_in[8];
    const int*   a2a      = (const int*)d_in[9];
    const int*   a2b      = (const int*)d_in[10];
    float* out = (float*)d_out;

    char* ws = (char*)d_ws;
    unsigned short* hA   = (unsigned short*)ws;                    // 20,480,000
    unsigned short* Zb   = (unsigned short*)(ws + 20480000);       // 40,960,000
    unsigned short* WtA  = (unsigned short*)(ws + 61440000);       // 262,144
    unsigned short* WtB  = (unsigned short*)(ws + 61702144);       // 131,072
    float* s_src_all     = (float*)(ws + 61833216);                // 640,000
    float* s_dst_all     = (float*)(ws + 62473216);                // 640,000
    float* score_edge    = (float*)(ws + 63113216);                // 6,400,000
    float* u_edge        = (float*)(ws + 69513216);                // 4,096
    float* c_edge        = (float*)(ws + 69517312);                // 32

    prep_kernel<<<772, 256, 0, stream>>>(W_atom, W_bond, att_edge, b_bond,
                                         WtA, WtB, u_edge, c_edge);

    // fused: atom GEMM (2504 blocks) + escore (6250 blocks)
    stage1_kernel<<<8754, 256, 0, stream>>>(x, WtA, b_atom, hA,
                                            edge, u_edge, c_edge, score_edge);

    sdots_kernel<<<5000, 256, 0, stream>>>(hA, att_src, att_dst, s_src_all, s_dst_all);

    attn_kernel<<<5000, 256, 0, stream>>>(
        hA, edge, s_src_all, s_dst_all, score_edge, a2a, a2b, out, Zb);

    proj_kernel<<<313 * 8, 256, 0, stream>>>(Zb, WtB, b_bond, out);
}